// Round 1
// baseline (280.071 us; speedup 1.0000x reference)
//
#include <hip/hip_runtime.h>
#include <hip/hip_bf16.h>

typedef __attribute__((ext_vector_type(8))) short bf16x8;
typedef __attribute__((ext_vector_type(4))) float f32x4;

#define LOG2E 1.4426950408889634f

__device__ __forceinline__ void gl_lds16(const void* g, void* l) {
  __builtin_amdgcn_global_load_lds((const __attribute__((address_space(1))) void*)g,
                                   (__attribute__((address_space(3))) void*)l, 16, 0, 0);
}

// ---- f32 -> bf16 cast (4 elems/thread) ----
__global__ __launch_bounds__(256) void cast_bf16_k(const float* __restrict__ in,
                                                   ushort* __restrict__ out, int n4) {
  int i = blockIdx.x * 256 + threadIdx.x;
  if (i >= n4) return;
  float4 f = ((const float4*)in)[i];
  ushort4 u;
  __hip_bfloat16 h;
  h = __float2bfloat16(f.x); u.x = *(ushort*)&h;
  h = __float2bfloat16(f.y); u.y = *(ushort*)&h;
  h = __float2bfloat16(f.z); u.z = *(ushort*)&h;
  h = __float2bfloat16(f.w); u.w = *(ushort*)&h;
  ((ushort4*)out)[i] = u;
}

// ---- C[M,N] = scale * A[M,K] @ B[N,K]^T ; bf16 in, bf16 or f32 out ----
template<int OUT_BF16>
__global__ __launch_bounds__(256)
void gemm_bt(const ushort* __restrict__ A, const ushort* __restrict__ B,
             void* __restrict__ C, int M, int N, int K, float scale) {
  __shared__ __attribute__((aligned(16))) ushort As[128 * 32];
  __shared__ __attribute__((aligned(16))) ushort Bs[128 * 32];
  const int t  = threadIdx.x;
  const int l  = t & 63;
  const int w  = t >> 6;
  const int lr = l & 15, lg = l >> 4;
  const int wr = (w >> 1) * 64, wc = (w & 1) * 64;
  const int bm = blockIdx.x * 128, bn = blockIdx.y * 128;

  f32x4 acc[4][4] = {};

  for (int kt = 0; kt < K; kt += 32) {
    __syncthreads();
    {
      int idx = t, row = idx >> 2, ch = idx & 3;
      gl_lds16(A + (size_t)(bm + row) * K + kt + ch * 8, As + idx * 8);
      gl_lds16(B + (size_t)(bn + row) * K + kt + ch * 8, Bs + idx * 8);
      idx = t + 256; row = idx >> 2; ch = idx & 3;
      gl_lds16(A + (size_t)(bm + row) * K + kt + ch * 8, As + idx * 8);
      gl_lds16(B + (size_t)(bn + row) * K + kt + ch * 8, Bs + idx * 8);
    }
    __syncthreads();
    bf16x8 af[4], bfr[4];
#pragma unroll
    for (int m = 0; m < 4; ++m)
      af[m] = *(const bf16x8*)&As[(wr + m * 16 + lr) * 32 + lg * 8];
#pragma unroll
    for (int n = 0; n < 4; ++n)
      bfr[n] = *(const bf16x8*)&Bs[(wc + n * 16 + lr) * 32 + lg * 8];
#pragma unroll
    for (int m = 0; m < 4; ++m)
#pragma unroll
      for (int n = 0; n < 4; ++n)
        acc[m][n] = __builtin_amdgcn_mfma_f32_16x16x32_bf16(af[m], bfr[n], acc[m][n], 0, 0, 0);
  }

#pragma unroll
  for (int m = 0; m < 4; ++m)
#pragma unroll
    for (int n = 0; n < 4; ++n)
#pragma unroll
      for (int j = 0; j < 4; ++j) {
        int row = bm + wr + m * 16 + lg * 4 + j;
        int col = bn + wc + n * 16 + lr;
        float v = acc[m][n][j] * scale;
        if (OUT_BF16) {
          __hip_bfloat16 h = __float2bfloat16(v);
          ((ushort*)C)[(size_t)row * N + col] = *(ushort*)&h;
        } else {
          ((float*)C)[(size_t)row * N + col] = v;
        }
      }
}

// ---- flash attention, causal + key-pad mask. Hd=64, 64 q-rows/block ----
__global__ __launch_bounds__(256)
void attn_k(const ushort* __restrict__ Q, const ushort* __restrict__ K,
            const ushort* __restrict__ V, const int* __restrict__ mask,
            ushort* __restrict__ O, int S, int D) {
  __shared__ __attribute__((aligned(16))) ushort Ks[64 * 64];      // XOR-swizzled rows
  __shared__ __attribute__((aligned(16))) ushort Vt[64 * 72];      // transposed [d][s], padded
  __shared__ __attribute__((aligned(16))) ushort Ps[4][16 * 72];   // per-wave P, padded
  __shared__ int Ms[64];

  const int t  = threadIdx.x;
  const int l  = t & 63, w = t >> 6;
  const int lr = l & 15, lg = l >> 4;
  const int qi = blockIdx.x;
  const int h  = blockIdx.y;
  const int b  = blockIdx.z;
  const size_t bS = (size_t)b * S;

  // Q fragments in registers (Q already scaled by 0.125)
  const ushort* qptr = Q + (bS + qi * 64 + w * 16 + lr) * D + h * 64;
  bf16x8 qf0 = *(const bf16x8*)(qptr + lg * 8);
  bf16x8 qf1 = *(const bf16x8*)(qptr + 32 + lg * 8);

  float m_[4], l_[4];
  f32x4 o[4] = {};
#pragma unroll
  for (int j = 0; j < 4; ++j) { m_[j] = -INFINITY; l_[j] = 0.f; }

  for (int kt = 0; kt <= qi; ++kt) {
    __syncthreads();
    // stage K (swizzled source so reads can XOR-deswizzle -> no 16-way conflicts)
    {
      int idx = t, row = idx >> 3, ch = idx & 7;
      gl_lds16(K + (bS + kt * 64 + row) * D + h * 64 + ((ch ^ (row & 7)) * 8), Ks + idx * 8);
      idx = t + 256; row = idx >> 3; ch = idx & 7;
      gl_lds16(K + (bS + kt * 64 + row) * D + h * 64 + ((ch ^ (row & 7)) * 8), Ks + idx * 8);
    }
    // stage V transposed into padded LDS
    {
      int sv = t >> 2, dg = (t & 3) * 16;
      const ushort* vp = V + (bS + kt * 64 + sv) * D + h * 64 + dg;
      bf16x8 v0 = *(const bf16x8*)vp;
      bf16x8 v1 = *(const bf16x8*)(vp + 8);
#pragma unroll
      for (int i = 0; i < 8; ++i) {
        Vt[(dg + i) * 72 + sv]     = (ushort)v0[i];
        Vt[(dg + 8 + i) * 72 + sv] = (ushort)v1[i];
      }
    }
    if (t < 64) Ms[t] = mask[bS + kt * 64 + t];
    __syncthreads();

    // QK^T: scores [16 q][64 k] per wave
    f32x4 s4[4];
#pragma unroll
    for (int c = 0; c < 4; ++c) {
      f32x4 sc = {0.f, 0.f, 0.f, 0.f};
      int row = c * 16 + lr;
      bf16x8 kf0 = *(const bf16x8*)&Ks[row * 64 + ((lg ^ (row & 7)) * 8)];
      bf16x8 kf1 = *(const bf16x8*)&Ks[row * 64 + (((4 + lg) ^ (row & 7)) * 8)];
      sc = __builtin_amdgcn_mfma_f32_16x16x32_bf16(qf0, kf0, sc, 0, 0, 0);
      sc = __builtin_amdgcn_mfma_f32_16x16x32_bf16(qf1, kf1, sc, 0, 0, 0);
      s4[c] = sc;
    }

    // causal + key-pad masking
    const int qrow0 = qi * 64 + w * 16 + lg * 4;
    const bool diag = (kt == qi);
#pragma unroll
    for (int c = 0; c < 4; ++c) {
      int kg = kt * 64 + c * 16 + lr;
      bool mz = (Ms[c * 16 + lr] == 0);
#pragma unroll
      for (int j = 0; j < 4; ++j)
        if ((diag && kg > qrow0 + j) || mz) s4[c][j] = -3.0e38f;
    }

    // online softmax (16-lane butterfly per row group)
    float p[4][4];
#pragma unroll
    for (int j = 0; j < 4; ++j) {
      float tm = fmaxf(fmaxf(s4[0][j], s4[1][j]), fmaxf(s4[2][j], s4[3][j]));
      tm = fmaxf(tm, __shfl_xor(tm, 1, 16));
      tm = fmaxf(tm, __shfl_xor(tm, 2, 16));
      tm = fmaxf(tm, __shfl_xor(tm, 4, 16));
      tm = fmaxf(tm, __shfl_xor(tm, 8, 16));
      float mn = fmaxf(m_[j], tm);
      float alpha = exp2f((m_[j] - mn) * LOG2E);
      float rs = 0.f;
#pragma unroll
      for (int c = 0; c < 4; ++c) {
        float pv = exp2f((s4[c][j] - mn) * LOG2E);
        p[c][j] = pv;
        rs += pv;
      }
      rs += __shfl_xor(rs, 1, 16);
      rs += __shfl_xor(rs, 2, 16);
      rs += __shfl_xor(rs, 4, 16);
      rs += __shfl_xor(rs, 8, 16);
      l_[j] = l_[j] * alpha + rs;
      m_[j] = mn;
#pragma unroll
      for (int c = 0; c < 4; ++c) o[c][j] *= alpha;
    }

    // P -> LDS (re-layout for PV A-operand)
#pragma unroll
    for (int c = 0; c < 4; ++c)
#pragma unroll
      for (int j = 0; j < 4; ++j) {
        __hip_bfloat16 hb = __float2bfloat16(p[c][j]);
        Ps[w][(lg * 4 + j) * 72 + c * 16 + lr] = *(ushort*)&hb;
      }
    __syncthreads();

    // PV
    bf16x8 pa0 = *(const bf16x8*)&Ps[w][lr * 72 + lg * 8];
    bf16x8 pa1 = *(const bf16x8*)&Ps[w][lr * 72 + 32 + lg * 8];
#pragma unroll
    for (int df = 0; df < 4; ++df) {
      bf16x8 vb0 = *(const bf16x8*)&Vt[(df * 16 + lr) * 72 + lg * 8];
      bf16x8 vb1 = *(const bf16x8*)&Vt[(df * 16 + lr) * 72 + 32 + lg * 8];
      o[df] = __builtin_amdgcn_mfma_f32_16x16x32_bf16(pa0, vb0, o[df], 0, 0, 0);
      o[df] = __builtin_amdgcn_mfma_f32_16x16x32_bf16(pa1, vb1, o[df], 0, 0, 0);
    }
  }

  // normalize + write bf16
#pragma unroll
  for (int j = 0; j < 4; ++j) {
    float inv = 1.0f / l_[j];
    size_t row = bS + qi * 64 + w * 16 + lg * 4 + j;
#pragma unroll
    for (int df = 0; df < 4; ++df) {
      __hip_bfloat16 hb = __float2bfloat16(o[df][j] * inv);
      O[row * D + h * 64 + df * 16 + lr] = *(ushort*)&hb;
    }
  }
}

extern "C" void kernel_launch(void* const* d_in, const int* in_sizes, int n_in,
                              void* d_out, int out_size, void* d_ws, size_t ws_size,
                              hipStream_t stream) {
  const float* x    = (const float*)d_in[0];
  const int*   mask = (const int*)d_in[1];
  const float* Wq   = (const float*)d_in[2];
  const float* Wk   = (const float*)d_in[3];
  const float* Wv   = (const float*)d_in[4];
  const float* Wo   = (const float*)d_in[5];
  float* out = (float*)d_out;

  const int B = 2, S = 2048, D = 1024, H = 16;
  const int M = B * S;

  char* ws = (char*)d_ws;
  ushort* xb  = (ushort*)(ws);
  ushort* wqb = (ushort*)(ws + (8ull  << 20));
  ushort* wkb = (ushort*)(ws + (10ull << 20));
  ushort* wvb = (ushort*)(ws + (12ull << 20));
  ushort* wob = (ushort*)(ws + (14ull << 20));
  ushort* Qb  = (ushort*)(ws + (16ull << 20));
  ushort* Kb  = (ushort*)(ws + (24ull << 20));
  ushort* Vb  = (ushort*)(ws + (32ull << 20));
  ushort* AO  = (ushort*)(ws + (40ull << 20));

  int nx4 = M * D / 4;
  int nw4 = D * D / 4;
  cast_bf16_k<<<(nx4 + 255) / 256, 256, 0, stream>>>(x,  xb,  nx4);
  cast_bf16_k<<<(nw4 + 255) / 256, 256, 0, stream>>>(Wq, wqb, nw4);
  cast_bf16_k<<<(nw4 + 255) / 256, 256, 0, stream>>>(Wk, wkb, nw4);
  cast_bf16_k<<<(nw4 + 255) / 256, 256, 0, stream>>>(Wv, wvb, nw4);
  cast_bf16_k<<<(nw4 + 255) / 256, 256, 0, stream>>>(Wo, wob, nw4);

  dim3 gp(M / 128, D / 128);  // 32 x 8
  gemm_bt<1><<<gp, 256, 0, stream>>>(xb, wqb, Qb, M, D, D, 0.125f);  // fold 1/sqrt(Hd)
  gemm_bt<1><<<gp, 256, 0, stream>>>(xb, wkb, Kb, M, D, D, 1.0f);
  gemm_bt<1><<<gp, 256, 0, stream>>>(xb, wvb, Vb, M, D, D, 1.0f);

  dim3 ga(S / 64, H, B);      // 32, 16, 2
  attn_k<<<ga, 256, 0, stream>>>(Qb, Kb, Vb, mask, AO, S, D);

  gemm_bt<0><<<gp, 256, 0, stream>>>(AO, wob, out, M, D, D, 1.0f);
}

// Round 4
// 162.881 us; speedup vs baseline: 1.7195x; 1.7195x over previous
//
#include <hip/hip_runtime.h>
#include <hip/hip_bf16.h>

typedef __attribute__((ext_vector_type(8))) short bf16x8;
typedef __attribute__((ext_vector_type(4))) short bf16x4;
typedef __attribute__((ext_vector_type(4))) float f32x4;

#define LOG2E 1.4426950408889634f
#define NEGF  -3.0e38f

__device__ __forceinline__ void gl_lds16(const void* g, void* l) {
  __builtin_amdgcn_global_load_lds((const __attribute__((address_space(1))) void*)g,
                                   (__attribute__((address_space(3))) void*)l, 16, 0, 0);
}

__device__ __forceinline__ ushort f2bu(float x) {
  __hip_bfloat16 h = __float2bfloat16(x);
  return *(ushort*)&h;
}

// ---- f32 -> bf16 cast for x ----
__global__ __launch_bounds__(256) void cast_bf16_k(const float* __restrict__ in,
                                                   ushort* __restrict__ out, int n4) {
  int i = blockIdx.x * 256 + threadIdx.x;
  if (i >= n4) return;
  float4 f = ((const float4*)in)[i];
  ushort4 u;
  u.x = f2bu(f.x); u.y = f2bu(f.y); u.z = f2bu(f.z); u.w = f2bu(f.w);
  ((ushort4*)out)[i] = u;
}

// ---- fused cast of the 4 weight matrices (each 1024x1024 = 2^18 float4) ----
__global__ __launch_bounds__(256) void cast_w4_k(const float* __restrict__ a, const float* __restrict__ b,
                                                 const float* __restrict__ c, const float* __restrict__ d,
                                                 ushort* __restrict__ oa, ushort* __restrict__ ob,
                                                 ushort* __restrict__ oc, ushort* __restrict__ od) {
  int i = blockIdx.x * 256 + threadIdx.x;
  int wsel = i >> 18, j = i & 262143;
  const float* src = wsel == 0 ? a : wsel == 1 ? b : wsel == 2 ? c : d;
  ushort* dst      = wsel == 0 ? oa : wsel == 1 ? ob : wsel == 2 ? oc : od;
  float4 f = ((const float4*)src)[j];
  ushort4 u;
  u.x = f2bu(f.x); u.y = f2bu(f.y); u.z = f2bu(f.z); u.w = f2bu(f.w);
  ((ushort4*)dst)[j] = u;
}

// ---- shared GEMM tile body: C = scale * A[M,K] @ B[N,K]^T ----
template<int OUT_BF16>
__device__ __forceinline__ void gemm_body(const ushort* __restrict__ A, const ushort* __restrict__ B,
                                          void* __restrict__ C, int M, int N, int Kd, float scale,
                                          int bm, int bn, ushort* As, ushort* Bs) {
  const int t  = threadIdx.x;
  const int l  = t & 63;
  const int w  = t >> 6;
  const int lr = l & 15, lg = l >> 4;
  const int wr = (w >> 1) * 64, wc = (w & 1) * 64;

  f32x4 acc[4][4] = {};

  for (int kt = 0; kt < Kd; kt += 32) {
    __syncthreads();
    {
      int idx = t, row = idx >> 2, ch = idx & 3;
      gl_lds16(A + (size_t)(bm + row) * Kd + kt + ch * 8, As + idx * 8);
      gl_lds16(B + (size_t)(bn + row) * Kd + kt + ch * 8, Bs + idx * 8);
      idx = t + 256; row = idx >> 2; ch = idx & 3;
      gl_lds16(A + (size_t)(bm + row) * Kd + kt + ch * 8, As + idx * 8);
      gl_lds16(B + (size_t)(bn + row) * Kd + kt + ch * 8, Bs + idx * 8);
    }
    __syncthreads();
    bf16x8 af[4], bfr[4];
#pragma unroll
    for (int m = 0; m < 4; ++m)
      af[m] = *(const bf16x8*)&As[(wr + m * 16 + lr) * 32 + lg * 8];
#pragma unroll
    for (int n = 0; n < 4; ++n)
      bfr[n] = *(const bf16x8*)&Bs[(wc + n * 16 + lr) * 32 + lg * 8];
#pragma unroll
    for (int m = 0; m < 4; ++m)
#pragma unroll
      for (int n = 0; n < 4; ++n)
        acc[m][n] = __builtin_amdgcn_mfma_f32_16x16x32_bf16(af[m], bfr[n], acc[m][n], 0, 0, 0);
  }

#pragma unroll
  for (int m = 0; m < 4; ++m)
#pragma unroll
    for (int n = 0; n < 4; ++n)
#pragma unroll
      for (int j = 0; j < 4; ++j) {
        int row = bm + wr + m * 16 + lg * 4 + j;
        int col = bn + wc + n * 16 + lr;
        float v = acc[m][n][j] * scale;
        if (OUT_BF16) {
          ((ushort*)C)[(size_t)row * N + col] = f2bu(v);
        } else {
          ((float*)C)[(size_t)row * N + col] = v;
        }
      }
}

__global__ __launch_bounds__(256)
void gemm_bt_f32(const ushort* __restrict__ A, const ushort* __restrict__ B, float* __restrict__ C,
                 int M, int N, int Kd, float scale) {
  __shared__ __attribute__((aligned(16))) ushort As[128 * 32];
  __shared__ __attribute__((aligned(16))) ushort Bs[128 * 32];
  gemm_body<0>(A, B, C, M, N, Kd, scale, blockIdx.x * 128, blockIdx.y * 128, As, Bs);
}

// fused QKV projection: grid.y in [0,24): y>>3 selects {Q,K,V}
__global__ __launch_bounds__(256)
void gemm_qkv(const ushort* __restrict__ A, const ushort* __restrict__ Wq, const ushort* __restrict__ Wk,
              const ushort* __restrict__ Wv, ushort* __restrict__ Qo, ushort* __restrict__ Ko,
              ushort* __restrict__ Vo, int M, int Kd) {
  __shared__ __attribute__((aligned(16))) ushort As[128 * 32];
  __shared__ __attribute__((aligned(16))) ushort Bs[128 * 32];
  int by = blockIdx.y;
  int which = by >> 3;
  const ushort* B = which == 0 ? Wq : which == 1 ? Wk : Wv;
  ushort* C       = which == 0 ? Qo : which == 1 ? Ko : Vo;
  float scale = which == 0 ? 0.125f : 1.0f;  // fold 1/sqrt(64) into Q
  gemm_body<1>(A, B, C, M, 1024, Kd, scale, blockIdx.x * 128, (by & 7) * 128, As, Bs);
}

// ---- flash attention: swapped QK^T, in-register softmax, tr-read V ----
// grid: 1024 flat blocks, balanced swizzle. 4 waves x 16 q-rows, KVBLK=64, Hd=64.
__global__ __launch_bounds__(256)
void attn_k(const ushort* __restrict__ Q, const ushort* __restrict__ K,
            const ushort* __restrict__ V, const int* __restrict__ mask,
            ushort* __restrict__ O) {
  const int S = 2048, D = 1024;
  __shared__ __attribute__((aligned(16))) ushort Ks[64 * 64];  // row-major, 16B-chunk XOR swizzle
  __shared__ __attribute__((aligned(16))) ushort Vs[64 * 64];  // subtiled [d>>4][k>>2][k&3][d&15]

  const int t = threadIdx.x;
  const int l = t & 63, w = t >> 6;
  const int lr = l & 15, lg = l >> 4;

  // balanced block swizzle: same-CU blocks (stride 256) pair qi with 31-qi -> equal k-tile totals
  int f = blockIdx.x;
  int r = f >> 8, g = f & 255, m0 = g & 31, n0 = g >> 5;
  int base = (m0 + (r >> 1) * 8) & 31;
  int qi = (r & 1) ? 31 - base : base;
  int hb = n0 + 8 * r;
  int h = hb & 15, b = hb >> 4;
  const size_t bS = (size_t)b * S;

  // Q fragments (B-operand of swapped QK^T); Q pre-scaled by 0.125
  const ushort* qptr = Q + (bS + qi * 64 + w * 16 + lr) * D + h * 64;
  bf16x8 qf0 = *(const bf16x8*)(qptr + lg * 8);
  bf16x8 qf1 = *(const bf16x8*)(qptr + 32 + lg * 8);

  const ushort* Kbh = K + bS * D + h * 64;
  const ushort* Vbh = V + bS * D + h * 64;
  const int* mbase = mask + bS;

  float m_ = -INFINITY, l_ = 0.f;
  f32x4 o[4] = {};

  for (int kt = 0; kt <= qi; ++kt) {
    __syncthreads();
    // stage K rows [64][64], swizzled 16B chunks (chunk' = chunk ^ (row&7))
    {
      int idx = t;       int row = idx >> 3, ch = idx & 7;
      gl_lds16(Kbh + (size_t)(kt * 64 + row) * D + ((ch ^ (row & 7)) * 8), Ks + idx * 8);
      idx = t + 256; row = idx >> 3; ch = idx & 7;
      gl_lds16(Kbh + (size_t)(kt * 64 + row) * D + ((ch ^ (row & 7)) * 8), Ks + idx * 8);
    }
    // stage V subtiled: elem(k,d) at (d>>4)*1024 + (k>>2)*64 + (k&3)*16 + (d&15)
    {
      int idx = t;  int dg = idx >> 7, kq = (idx >> 3) & 15, jj = (idx >> 1) & 3, hf = idx & 1;
      gl_lds16(Vbh + (size_t)(kt * 64 + kq * 4 + jj) * D + dg * 16 + hf * 8, Vs + idx * 8);
      idx = t + 256; dg = idx >> 7; kq = (idx >> 3) & 15; jj = (idx >> 1) & 3; hf = idx & 1;
      gl_lds16(Vbh + (size_t)(kt * 64 + kq * 4 + jj) * D + dg * 16 + hf * 8, Vs + idx * 8);
    }
    unsigned long long mb = __ballot(mbase[kt * 64 + l] != 0);
    __syncthreads();

    const bool diag = (kt == qi);
    const int cmax = diag ? w : 3;

    // swapped QK^T: s4[c][j] = S[q = w*16+lr][k = c*16 + lg*4 + j]
    f32x4 s4[4];
#pragma unroll
    for (int c = 0; c < 4; ++c) {
      if (c <= cmax) {
        int row = c * 16 + lr;
        bf16x8 kf0 = *(const bf16x8*)&Ks[row * 64 + ((lg ^ (row & 7)) << 3)];
        bf16x8 kf1 = *(const bf16x8*)&Ks[row * 64 + (((4 + lg) ^ (row & 7)) << 3)];
        f32x4 sc = {0.f, 0.f, 0.f, 0.f};
        sc = __builtin_amdgcn_mfma_f32_16x16x32_bf16(kf0, qf0, sc, 0, 0, 0);
        sc = __builtin_amdgcn_mfma_f32_16x16x32_bf16(kf1, qf1, sc, 0, 0, 0);
        if (diag && c == cmax) {  // only the c==w tile needs element-wise causal mask
          int qg = w * 16 + lr;
          int kb = c * 16 + lg * 4;
#pragma unroll
          for (int j = 0; j < 4; ++j)
            if (kb + j > qg) sc[j] = NEGF;
        }
        s4[c] = sc;
      } else {
        s4[c] = (f32x4){NEGF, NEGF, NEGF, NEGF};
      }
    }

    // key-pad mask (skipped entirely when mask is all ones)
    if (~mb != 0ull) {
#pragma unroll
      for (int c = 0; c < 4; ++c)
#pragma unroll
        for (int j = 0; j < 4; ++j)
          if (!((mb >> (c * 16 + lg * 4 + j)) & 1)) s4[c][j] = NEGF;
    }

    // in-register online softmax for q = lr (k-values spread across the 4 lg lanes)
    float tm = NEGF;
#pragma unroll
    for (int c = 0; c < 4; ++c)
#pragma unroll
      for (int j = 0; j < 4; ++j) tm = fmaxf(tm, s4[c][j]);
    tm = fmaxf(tm, __shfl_xor(tm, 16));
    tm = fmaxf(tm, __shfl_xor(tm, 32));

    bool need = !__all(tm - m_ <= 8.0f);  // defer-max (T13)
    float mn = need ? fmaxf(m_, tm) : m_;
    float scl = mn * LOG2E;
    if (need) {
      float alpha = exp2f(m_ * LOG2E - scl);
      m_ = mn;
      l_ *= alpha;
      float a0 = __shfl(alpha, lg * 4 + 0, 16);
      float a1 = __shfl(alpha, lg * 4 + 1, 16);
      float a2 = __shfl(alpha, lg * 4 + 2, 16);
      float a3 = __shfl(alpha, lg * 4 + 3, 16);
#pragma unroll
      for (int dt = 0; dt < 4; ++dt) {
        o[dt][0] *= a0; o[dt][1] *= a1; o[dt][2] *= a2; o[dt][3] *= a3;
      }
    }

    float rs = 0.f;
#pragma unroll
    for (int c = 0; c < 4; ++c)
#pragma unroll
      for (int j = 0; j < 4; ++j) {
        float p = exp2f(s4[c][j] * LOG2E - scl);
        rs += p;
        s4[c][j] = p;
      }
    rs += __shfl_xor(rs, 16);
    rs += __shfl_xor(rs, 32);
    l_ += rs;

    // pack P to bf16 A-frags in registers (slot sigma: (lg, i) -> k = (i>>2)*16 + lg*4 + (i&3))
    union { bf16x8 v; ushort u[8]; } pa0, pa1;
#pragma unroll
    for (int j = 0; j < 4; ++j) {
      pa0.u[j]     = f2bu(s4[0][j]);
      pa0.u[4 + j] = f2bu(s4[1][j]);
      pa1.u[j]     = f2bu(s4[2][j]);
      pa1.u[4 + j] = f2bu(s4[3][j]);
    }

    // PV: B-frags via hardware transpose reads. Natural tr-addressing: each lane fetches
    // 8 CONTIGUOUS bytes at base + (l>>4)*128B + (l&15)*8B; the 16-lane group's 64-element
    // span is delivered transposed: lane l elem j = span[(l&15) + 16*j]. waitcnt fused in.
#pragma unroll
    for (int dt = 0; dt < 4; ++dt) {
      const __attribute__((address_space(3))) ushort* vp =
          (const __attribute__((address_space(3))) ushort*)Vs + dt * 1024 + lg * 64 + lr * 4;
      bf16x4 h0, h1, h2, h3;
      asm volatile(
          "ds_read_b64_tr_b16 %0, %4\n\t"
          "ds_read_b64_tr_b16 %1, %4 offset:512\n\t"
          "ds_read_b64_tr_b16 %2, %4 offset:1024\n\t"
          "ds_read_b64_tr_b16 %3, %4 offset:1536\n\t"
          "s_waitcnt lgkmcnt(0)"
          : "=&v"(h0), "=&v"(h1), "=&v"(h2), "=&v"(h3)
          : "v"(vp));
      bf16x8 vb0 = __builtin_shufflevector(h0, h1, 0, 1, 2, 3, 4, 5, 6, 7);
      bf16x8 vb1 = __builtin_shufflevector(h2, h3, 0, 1, 2, 3, 4, 5, 6, 7);
      o[dt] = __builtin_amdgcn_mfma_f32_16x16x32_bf16(pa0.v, vb0, o[dt], 0, 0, 0);
      o[dt] = __builtin_amdgcn_mfma_f32_16x16x32_bf16(pa1.v, vb1, o[dt], 0, 0, 0);
    }
  }

  // normalize (l_ lives at q=lr; o rows are q=lg*4+j) and write bf16
  float inv = 1.0f / l_;
  float v0 = __shfl(inv, lg * 4 + 0, 16);
  float v1 = __shfl(inv, lg * 4 + 1, 16);
  float v2 = __shfl(inv, lg * 4 + 2, 16);
  float v3 = __shfl(inv, lg * 4 + 3, 16);
#pragma unroll
  for (int dt = 0; dt < 4; ++dt) {
    size_t col = (size_t)h * 64 + dt * 16 + lr;
    size_t r0 = bS + qi * 64 + w * 16 + lg * 4;
    O[(r0 + 0) * D + col] = f2bu(o[dt][0] * v0);
    O[(r0 + 1) * D + col] = f2bu(o[dt][1] * v1);
    O[(r0 + 2) * D + col] = f2bu(o[dt][2] * v2);
    O[(r0 + 3) * D + col] = f2bu(o[dt][3] * v3);
  }
}

extern "C" void kernel_launch(void* const* d_in, const int* in_sizes, int n_in,
                              void* d_out, int out_size, void* d_ws, size_t ws_size,
                              hipStream_t stream) {
  const float* x    = (const float*)d_in[0];
  const int*   mask = (const int*)d_in[1];
  const float* Wq   = (const float*)d_in[2];
  const float* Wk   = (const float*)d_in[3];
  const float* Wv   = (const float*)d_in[4];
  const float* Wo   = (const float*)d_in[5];
  float* out = (float*)d_out;

  const int B = 2, S = 2048, D = 1024;
  const int M = B * S;

  // 48 MB peak (same footprint round 1 proved fits in d_ws)
  char* ws = (char*)d_ws;
  ushort* xb  = (ushort*)(ws);                  // 8 MB
  ushort* wqb = (ushort*)(ws + (8ull  << 20));  // 2 MB
  ushort* wkb = (ushort*)(ws + (10ull << 20));
  ushort* wvb = (ushort*)(ws + (12ull << 20));
  ushort* wob = (ushort*)(ws + (14ull << 20));
  ushort* Qb  = (ushort*)(ws + (16ull << 20));  // 8 MB
  ushort* Kb  = (ushort*)(ws + (24ull << 20));
  ushort* Vb  = (ushort*)(ws + (32ull << 20));
  ushort* AO  = (ushort*)(ws + (40ull << 20));

  int nx4 = M * D / 4;  // 1048576
  cast_bf16_k<<<(nx4 + 255) / 256, 256, 0, stream>>>(x, xb, nx4);
  cast_w4_k<<<4096, 256, 0, stream>>>(Wq, Wk, Wv, Wo, wqb, wkb, wvb, wob);

  dim3 gq(M / 128, 24);
  gemm_qkv<<<gq, 256, 0, stream>>>(xb, wqb, wkb, wvb, Qb, Kb, Vb, M, D);

  attn_k<<<1024, 256, 0, stream>>>(Qb, Kb, Vb, mask, AO);

  dim3 gp(M / 128, D / 128);
  gemm_bt_f32<<<gp, 256, 0, stream>>>(AO, wob, out, M, D, D, 1.0f);
}

// Round 5
// 144.102 us; speedup vs baseline: 1.9436x; 1.1303x over previous
//
#include <hip/hip_runtime.h>
#include <hip/hip_bf16.h>

typedef __attribute__((ext_vector_type(8))) short bf16x8;
typedef __attribute__((ext_vector_type(4))) short bf16x4;
typedef __attribute__((ext_vector_type(4))) float f32x4;

#define LOG2E 1.4426950408889634f
#define NEGF  -3.0e38f

__device__ __forceinline__ void gl_lds16(const void* g, void* l) {
  __builtin_amdgcn_global_load_lds((const __attribute__((address_space(1))) void*)g,
                                   (__attribute__((address_space(3))) void*)l, 16, 0, 0);
}

__device__ __forceinline__ ushort f2bu(float x) {
  __hip_bfloat16 h = __float2bfloat16(x);
  return *(ushort*)&h;
}

// ---- f32 -> bf16 cast for x ----
__global__ __launch_bounds__(256) void cast_bf16_k(const float* __restrict__ in,
                                                   ushort* __restrict__ out, int n4) {
  int i = blockIdx.x * 256 + threadIdx.x;
  if (i >= n4) return;
  float4 f = ((const float4*)in)[i];
  ushort4 u;
  u.x = f2bu(f.x); u.y = f2bu(f.y); u.z = f2bu(f.z); u.w = f2bu(f.w);
  ((ushort4*)out)[i] = u;
}

// ---- fused cast of the 4 weight matrices (each 1024x1024 = 2^18 float4) ----
__global__ __launch_bounds__(256) void cast_w4_k(const float* __restrict__ a, const float* __restrict__ b,
                                                 const float* __restrict__ c, const float* __restrict__ d,
                                                 ushort* __restrict__ oa, ushort* __restrict__ ob,
                                                 ushort* __restrict__ oc, ushort* __restrict__ od) {
  int i = blockIdx.x * 256 + threadIdx.x;
  int wsel = i >> 18, j = i & 262143;
  const float* src = wsel == 0 ? a : wsel == 1 ? b : wsel == 2 ? c : d;
  ushort* dst      = wsel == 0 ? oa : wsel == 1 ? ob : wsel == 2 ? oc : od;
  float4 f = ((const float4*)src)[j];
  ushort4 u;
  u.x = f2bu(f.x); u.y = f2bu(f.y); u.z = f2bu(f.z); u.w = f2bu(f.w);
  ((ushort4*)dst)[j] = u;
}

// ---- shared GEMM tile body: C = scale * A[M,K] @ B[N,K]^T ----
template<int OUT_BF16>
__device__ __forceinline__ void gemm_body(const ushort* __restrict__ A, const ushort* __restrict__ B,
                                          void* __restrict__ C, int M, int N, int Kd, float scale,
                                          int bm, int bn, ushort* As, ushort* Bs) {
  const int t  = threadIdx.x;
  const int l  = t & 63;
  const int w  = t >> 6;
  const int lr = l & 15, lg = l >> 4;
  const int wr = (w >> 1) * 64, wc = (w & 1) * 64;

  f32x4 acc[4][4] = {};

  for (int kt = 0; kt < Kd; kt += 32) {
    __syncthreads();
    {
      int idx = t, row = idx >> 2, ch = idx & 3;
      gl_lds16(A + (size_t)(bm + row) * Kd + kt + ch * 8, As + idx * 8);
      gl_lds16(B + (size_t)(bn + row) * Kd + kt + ch * 8, Bs + idx * 8);
      idx = t + 256; row = idx >> 2; ch = idx & 3;
      gl_lds16(A + (size_t)(bm + row) * Kd + kt + ch * 8, As + idx * 8);
      gl_lds16(B + (size_t)(bn + row) * Kd + kt + ch * 8, Bs + idx * 8);
    }
    __syncthreads();
    bf16x8 af[4], bfr[4];
#pragma unroll
    for (int m = 0; m < 4; ++m)
      af[m] = *(const bf16x8*)&As[(wr + m * 16 + lr) * 32 + lg * 8];
#pragma unroll
    for (int n = 0; n < 4; ++n)
      bfr[n] = *(const bf16x8*)&Bs[(wc + n * 16 + lr) * 32 + lg * 8];
#pragma unroll
    for (int m = 0; m < 4; ++m)
#pragma unroll
      for (int n = 0; n < 4; ++n)
        acc[m][n] = __builtin_amdgcn_mfma_f32_16x16x32_bf16(af[m], bfr[n], acc[m][n], 0, 0, 0);
  }

#pragma unroll
  for (int m = 0; m < 4; ++m)
#pragma unroll
    for (int n = 0; n < 4; ++n)
#pragma unroll
      for (int j = 0; j < 4; ++j) {
        int row = bm + wr + m * 16 + lg * 4 + j;
        int col = bn + wc + n * 16 + lr;
        float v = acc[m][n][j] * scale;
        if (OUT_BF16) {
          ((ushort*)C)[(size_t)row * N + col] = f2bu(v);
        } else {
          ((float*)C)[(size_t)row * N + col] = v;
        }
      }
}

__global__ __launch_bounds__(256)
void gemm_bt_f32(const ushort* __restrict__ A, const ushort* __restrict__ B, float* __restrict__ C,
                 int M, int N, int Kd, float scale) {
  __shared__ __attribute__((aligned(16))) ushort As[128 * 32];
  __shared__ __attribute__((aligned(16))) ushort Bs[128 * 32];
  gemm_body<0>(A, B, C, M, N, Kd, scale, blockIdx.x * 128, blockIdx.y * 128, As, Bs);
}

// fused QKV projection: grid.y in [0,24): y>>3 selects {Q,K,V}
__global__ __launch_bounds__(256)
void gemm_qkv(const ushort* __restrict__ A, const ushort* __restrict__ Wq, const ushort* __restrict__ Wk,
              const ushort* __restrict__ Wv, ushort* __restrict__ Qo, ushort* __restrict__ Ko,
              ushort* __restrict__ Vo, int M, int Kd) {
  __shared__ __attribute__((aligned(16))) ushort As[128 * 32];
  __shared__ __attribute__((aligned(16))) ushort Bs[128 * 32];
  int by = blockIdx.y;
  int which = by >> 3;
  const ushort* B = which == 0 ? Wq : which == 1 ? Wk : Wv;
  ushort* C       = which == 0 ? Qo : which == 1 ? Ko : Vo;
  float scale = which == 0 ? 0.125f : 1.0f;  // fold 1/sqrt(64) into Q
  gemm_body<1>(A, B, C, M, 1024, Kd, scale, blockIdx.x * 128, (by & 7) * 128, As, Bs);
}

// online softmax over one 64-wide score tile held as s4[c][j] (k = c*16+lg*4+j, q = w*16+lr).
// Updates (m_, l_, o[4]); packs P into pa0/pa1. All-static indexing.
__device__ __forceinline__ void online_sm(f32x4 s4[4], float& m_, float& l_, f32x4 o[4],
                                          int lg, bf16x8& pa0_out, bf16x8& pa1_out) {
  float tm = NEGF;
#pragma unroll
  for (int c = 0; c < 4; ++c)
#pragma unroll
    for (int j = 0; j < 4; ++j) tm = fmaxf(tm, s4[c][j]);
  tm = fmaxf(tm, __shfl_xor(tm, 16));
  tm = fmaxf(tm, __shfl_xor(tm, 32));

  bool need = !__all(tm - m_ <= 8.0f);  // defer-max (T13)
  float mn = need ? fmaxf(m_, tm) : m_;
  float scl = mn * LOG2E;
  if (need) {
    float alpha = exp2f(m_ * LOG2E - scl);
    m_ = mn;
    l_ *= alpha;
    float a0 = __shfl(alpha, lg * 4 + 0, 16);
    float a1 = __shfl(alpha, lg * 4 + 1, 16);
    float a2 = __shfl(alpha, lg * 4 + 2, 16);
    float a3 = __shfl(alpha, lg * 4 + 3, 16);
#pragma unroll
    for (int dt = 0; dt < 4; ++dt) {
      o[dt][0] *= a0; o[dt][1] *= a1; o[dt][2] *= a2; o[dt][3] *= a3;
    }
  }

  float rs = 0.f;
#pragma unroll
  for (int c = 0; c < 4; ++c)
#pragma unroll
    for (int j = 0; j < 4; ++j) {
      float p = exp2f(s4[c][j] * LOG2E - scl);
      rs += p;
      s4[c][j] = p;
    }
  rs += __shfl_xor(rs, 16);
  rs += __shfl_xor(rs, 32);
  l_ += rs;

  union { bf16x8 v; ushort u[8]; } pa0, pa1;
#pragma unroll
  for (int j = 0; j < 4; ++j) {
    pa0.u[j]     = f2bu(s4[0][j]);
    pa0.u[4 + j] = f2bu(s4[1][j]);
    pa1.u[j]     = f2bu(s4[2][j]);
    pa1.u[4 + j] = f2bu(s4[3][j]);
  }
  pa0_out = pa0.v;
  pa1_out = pa1.v;
}

// ---- flash attention: paired q-tiles (p, 31-p), double-buffered K/V, counted vmcnt ----
// grid: 512 blocks = 16 pairs x 32 (b,h). 4 waves x 16 q-rows per tile, KVBLK=64, Hd=64.
__global__ __launch_bounds__(256)
void attn_k(const ushort* __restrict__ Q, const ushort* __restrict__ K,
            const ushort* __restrict__ V, const int* __restrict__ mask,
            ushort* __restrict__ O) {
  const int S = 2048, D = 1024;
  __shared__ __attribute__((aligned(16))) ushort Ks[2][4096];  // 16B-chunk XOR-swizzled rows
  __shared__ __attribute__((aligned(16))) ushort Vs[2][4096];  // subtiled [d>>4][k>>2][k&3][d&15]
  __shared__ unsigned long long Msb[32];

  const int t = threadIdx.x;
  const int l = t & 63, w = t >> 6;
  const int lr = l & 15, lg = l >> 4;

  // decode: f = (bh&7) + 8*p + 128*(bh>>3)  -> same (b,h) => same f%8 (XCD L2 locality)
  int f = blockIdx.x;
  int p  = (f >> 3) & 15;
  int bh = (f & 7) | ((f >> 7) << 3);
  int h = bh & 15, b = bh >> 4;
  const int qA = p, qB = 31 - p;   // two q-tiles; total k-tiles = 33 for every block
  const int nt = qB + 1;
  const size_t bS = (size_t)b * S;

  const ushort* qptrA = Q + (bS + qA * 64 + w * 16 + lr) * D + h * 64;
  const ushort* qptrB = Q + (bS + qB * 64 + w * 16 + lr) * D + h * 64;
  bf16x8 qfA0 = *(const bf16x8*)(qptrA + lg * 8);
  bf16x8 qfA1 = *(const bf16x8*)(qptrA + 32 + lg * 8);
  bf16x8 qfB0 = *(const bf16x8*)(qptrB + lg * 8);
  bf16x8 qfB1 = *(const bf16x8*)(qptrB + 32 + lg * 8);

  const ushort* Kbh = K + bS * D + h * 64;
  const ushort* Vbh = V + bS * D + h * 64;
  const int* mbase = mask + bS;

  // precompute per-tile key-pad ballots (removes all non-staging VMEM from the main loop)
  for (int kk = w; kk < nt; kk += 4) {
    unsigned long long mb = __ballot(mbase[kk * 64 + l] != 0);
    if (l == 0) Msb[kk] = mb;
  }

  float mA = -INFINITY, lA = 0.f, mB = -INFINITY, lB = 0.f;
  f32x4 oA[4] = {}, oB[4] = {};

  // stage(buf, kt): 4 global_load_lds per thread (2 K chunks + 2 V chunks)
  auto stage = [&](int buf, int kt) {
    {
      int idx = t;       int row = idx >> 3, ch = idx & 7;
      gl_lds16(Kbh + (size_t)(kt * 64 + row) * D + ((ch ^ (row & 7)) * 8), &Ks[buf][idx * 8]);
      idx = t + 256; row = idx >> 3; ch = idx & 7;
      gl_lds16(Kbh + (size_t)(kt * 64 + row) * D + ((ch ^ (row & 7)) * 8), &Ks[buf][idx * 8]);
    }
    {
      int idx = t;  int dg = idx >> 7, kq = (idx >> 3) & 15, jj = (idx >> 1) & 3, hf = idx & 1;
      gl_lds16(Vbh + (size_t)(kt * 64 + kq * 4 + jj) * D + dg * 16 + hf * 8, &Vs[buf][idx * 8]);
      idx = t + 256; dg = idx >> 7; kq = (idx >> 3) & 15; jj = (idx >> 1) & 3; hf = idx & 1;
      gl_lds16(Vbh + (size_t)(kt * 64 + kq * 4 + jj) * D + dg * 16 + hf * 8, &Vs[buf][idx * 8]);
    }
  };

  stage(0, 0);

  for (int kt = 0; kt < nt; ++kt) {
    const int cur = kt & 1;
    // T3/T4: issue next tile's loads, then wait ONLY for the current tile's 4 loads.
    // In-loop VMEM = staging only (Q/mask preloaded), so the count is exact.
    if (kt + 1 < nt) {
      stage(cur ^ 1, kt + 1);
      asm volatile("s_waitcnt vmcnt(4) lgkmcnt(0)" ::: "memory");
    } else {
      asm volatile("s_waitcnt vmcnt(0) lgkmcnt(0)" ::: "memory");
    }
    __builtin_amdgcn_s_barrier();   // all waves: cur buffer staged

    unsigned long long mb = Msb[kt];
    const bool actA  = (kt <= qA);
    const bool diagA = (kt == qA), diagB = (kt == qB);

    // swapped QK^T; K-fragments shared between both q-tiles
    f32x4 sA[4], sB[4];
#pragma unroll
    for (int c = 0; c < 4; ++c) {
      int row = c * 16 + lr;
      bf16x8 kf0 = *(const bf16x8*)&Ks[cur][row * 64 + ((lg ^ (row & 7)) << 3)];
      bf16x8 kf1 = *(const bf16x8*)&Ks[cur][row * 64 + (((4 + lg) ^ (row & 7)) << 3)];
      // B tile (always active)
      if (!diagB || c <= w) {
        f32x4 sc = {0.f, 0.f, 0.f, 0.f};
        sc = __builtin_amdgcn_mfma_f32_16x16x32_bf16(kf0, qfB0, sc, 0, 0, 0);
        sc = __builtin_amdgcn_mfma_f32_16x16x32_bf16(kf1, qfB1, sc, 0, 0, 0);
        if (diagB && c == w) {
          int qg = w * 16 + lr, kb = c * 16 + lg * 4;
#pragma unroll
          for (int j = 0; j < 4; ++j)
            if (kb + j > qg) sc[j] = NEGF;
        }
        sB[c] = sc;
      } else {
        sB[c] = (f32x4){NEGF, NEGF, NEGF, NEGF};
      }
      // A tile
      if (actA) {
        if (!diagA || c <= w) {
          f32x4 sc = {0.f, 0.f, 0.f, 0.f};
          sc = __builtin_amdgcn_mfma_f32_16x16x32_bf16(kf0, qfA0, sc, 0, 0, 0);
          sc = __builtin_amdgcn_mfma_f32_16x16x32_bf16(kf1, qfA1, sc, 0, 0, 0);
          if (diagA && c == w) {
            int qg = w * 16 + lr, kb = c * 16 + lg * 4;
#pragma unroll
            for (int j = 0; j < 4; ++j)
              if (kb + j > qg) sc[j] = NEGF;
          }
          sA[c] = sc;
        } else {
          sA[c] = (f32x4){NEGF, NEGF, NEGF, NEGF};
        }
      }
    }

    // key-pad mask (skipped when all ones)
    if (~mb != 0ull) {
#pragma unroll
      for (int c = 0; c < 4; ++c)
#pragma unroll
        for (int j = 0; j < 4; ++j) {
          bool z = !((mb >> (c * 16 + lg * 4 + j)) & 1);
          if (z) sB[c][j] = NEGF;
          if (actA && z) sA[c][j] = NEGF;
        }
    }

    bf16x8 paB0, paB1, paA0, paA1;
    online_sm(sB, mB, lB, oB, lg, paB0, paB1);
    if (actA) online_sm(sA, mA, lA, oA, lg, paA0, paA1);

    // PV: tr-read V fragments once, feed BOTH accumulators
#pragma unroll
    for (int dt = 0; dt < 4; ++dt) {
      const __attribute__((address_space(3))) ushort* vp =
          (const __attribute__((address_space(3))) ushort*)&Vs[cur][0] + dt * 1024 + lg * 64 + lr * 4;
      bf16x4 h0, h1, h2, h3;
      asm volatile(
          "ds_read_b64_tr_b16 %0, %4\n\t"
          "ds_read_b64_tr_b16 %1, %4 offset:512\n\t"
          "ds_read_b64_tr_b16 %2, %4 offset:1024\n\t"
          "ds_read_b64_tr_b16 %3, %4 offset:1536\n\t"
          "s_waitcnt lgkmcnt(0)"
          : "=&v"(h0), "=&v"(h1), "=&v"(h2), "=&v"(h3)
          : "v"(vp));
      bf16x8 vb0 = __builtin_shufflevector(h0, h1, 0, 1, 2, 3, 4, 5, 6, 7);
      bf16x8 vb1 = __builtin_shufflevector(h2, h3, 0, 1, 2, 3, 4, 5, 6, 7);
      oB[dt] = __builtin_amdgcn_mfma_f32_16x16x32_bf16(paB0, vb0, oB[dt], 0, 0, 0);
      oB[dt] = __builtin_amdgcn_mfma_f32_16x16x32_bf16(paB1, vb1, oB[dt], 0, 0, 0);
      if (actA) {
        oA[dt] = __builtin_amdgcn_mfma_f32_16x16x32_bf16(paA0, vb0, oA[dt], 0, 0, 0);
        oA[dt] = __builtin_amdgcn_mfma_f32_16x16x32_bf16(paA1, vb1, oA[dt], 0, 0, 0);
      }
    }

    __builtin_amdgcn_s_barrier();   // all reads of cur done before next iter overwrites it
  }

  // epilogue: normalize and write both tiles
#pragma unroll
  for (int tile = 0; tile < 2; ++tile) {
    float l_ = tile ? lB : lA;
    f32x4* o = tile ? oB : oA;
    int qi   = tile ? qB : qA;
    float inv = 1.0f / l_;
    float v0 = __shfl(inv, lg * 4 + 0, 16);
    float v1 = __shfl(inv, lg * 4 + 1, 16);
    float v2 = __shfl(inv, lg * 4 + 2, 16);
    float v3 = __shfl(inv, lg * 4 + 3, 16);
#pragma unroll
    for (int dt = 0; dt < 4; ++dt) {
      size_t col = (size_t)h * 64 + dt * 16 + lr;
      size_t r0 = bS + qi * 64 + w * 16 + lg * 4;
      O[(r0 + 0) * D + col] = f2bu(o[dt][0] * v0);
      O[(r0 + 1) * D + col] = f2bu(o[dt][1] * v1);
      O[(r0 + 2) * D + col] = f2bu(o[dt][2] * v2);
      O[(r0 + 3) * D + col] = f2bu(o[dt][3] * v3);
    }
  }
}

extern "C" void kernel_launch(void* const* d_in, const int* in_sizes, int n_in,
                              void* d_out, int out_size, void* d_ws, size_t ws_size,
                              hipStream_t stream) {
  const float* x    = (const float*)d_in[0];
  const int*   mask = (const int*)d_in[1];
  const float* Wq   = (const float*)d_in[2];
  const float* Wk   = (const float*)d_in[3];
  const float* Wv   = (const float*)d_in[4];
  const float* Wo   = (const float*)d_in[5];
  float* out = (float*)d_out;

  const int B = 2, S = 2048, D = 1024;
  const int M = B * S;

  // 48 MB peak (proven footprint)
  char* ws = (char*)d_ws;
  ushort* xb  = (ushort*)(ws);                  // 8 MB
  ushort* wqb = (ushort*)(ws + (8ull  << 20));  // 2 MB
  ushort* wkb = (ushort*)(ws + (10ull << 20));
  ushort* wvb = (ushort*)(ws + (12ull << 20));
  ushort* wob = (ushort*)(ws + (14ull << 20));
  ushort* Qb  = (ushort*)(ws + (16ull << 20));  // 8 MB
  ushort* Kb  = (ushort*)(ws + (24ull << 20));
  ushort* Vb  = (ushort*)(ws + (32ull << 20));
  ushort* AO  = (ushort*)(ws + (40ull << 20));

  int nx4 = M * D / 4;  // 1048576
  cast_bf16_k<<<(nx4 + 255) / 256, 256, 0, stream>>>(x, xb, nx4);
  cast_w4_k<<<4096, 256, 0, stream>>>(Wq, Wk, Wv, Wo, wqb, wkb, wvb, wob);

  dim3 gq(M / 128, 24);
  gemm_qkv<<<gq, 256, 0, stream>>>(xb, wqb, wkb, wvb, Qb, Kb, Vb, M, D);

  attn_k<<<512, 256, 0, stream>>>(Qb, Kb, Vb, mask, AO);

  dim3 gp(M / 128, D / 128);
  gemm_bt_f32<<<gp, 256, 0, stream>>>(AO, wob, out, M, D, D, 1.0f);
}

// Round 6
// 127.267 us; speedup vs baseline: 2.2007x; 1.1323x over previous
//
#include <hip/hip_runtime.h>
#include <hip/hip_bf16.h>

typedef __attribute__((ext_vector_type(8))) short bf16x8;
typedef __attribute__((ext_vector_type(4))) short bf16x4;
typedef __attribute__((ext_vector_type(4))) float f32x4;

#define LOG2E 1.4426950408889634f
#define NEGF  -3.0e38f

__device__ __forceinline__ void gl_lds16(const void* g, void* l) {
  __builtin_amdgcn_global_load_lds((const __attribute__((address_space(1))) void*)g,
                                   (__attribute__((address_space(3))) void*)l, 16, 0, 0);
}

__device__ __forceinline__ ushort f2bu(float x) {
  __hip_bfloat16 h = __float2bfloat16(x);
  return *(ushort*)&h;
}

// ---- f32 -> bf16 cast for x ----
__global__ __launch_bounds__(256) void cast_bf16_k(const float* __restrict__ in,
                                                   ushort* __restrict__ out, int n4) {
  int i = blockIdx.x * 256 + threadIdx.x;
  if (i >= n4) return;
  float4 f = ((const float4*)in)[i];
  ushort4 u;
  u.x = f2bu(f.x); u.y = f2bu(f.y); u.z = f2bu(f.z); u.w = f2bu(f.w);
  ((ushort4*)out)[i] = u;
}

// ---- fused cast of the 4 weight matrices (each 1024x1024 = 2^18 float4) ----
__global__ __launch_bounds__(256) void cast_w4_k(const float* __restrict__ a, const float* __restrict__ b,
                                                 const float* __restrict__ c, const float* __restrict__ d,
                                                 ushort* __restrict__ oa, ushort* __restrict__ ob,
                                                 ushort* __restrict__ oc, ushort* __restrict__ od) {
  int i = blockIdx.x * 256 + threadIdx.x;
  int wsel = i >> 18, j = i & 262143;
  const float* src = wsel == 0 ? a : wsel == 1 ? b : wsel == 2 ? c : d;
  ushort* dst      = wsel == 0 ? oa : wsel == 1 ? ob : wsel == 2 ? oc : od;
  float4 f = ((const float4*)src)[j];
  ushort4 u;
  u.x = f2bu(f.x); u.y = f2bu(f.y); u.z = f2bu(f.z); u.w = f2bu(f.w);
  ((ushort4*)dst)[j] = u;
}

// ---- GEMM tile body: C = scale * A[M,K] @ B[N,K]^T ; double-buffered, counted vmcnt ----
template<int OUT_BF16>
__device__ __forceinline__ void gemm_body(const ushort* __restrict__ A, const ushort* __restrict__ B,
                                          void* __restrict__ C, int M, int N, int Kd, float scale,
                                          int bm, int bn, ushort (*As)[4096], ushort (*Bs)[4096]) {
  const int t  = threadIdx.x;
  const int l  = t & 63;
  const int w  = t >> 6;
  const int lr = l & 15, lg = l >> 4;
  const int wr = (w >> 1) * 64, wc = (w & 1) * 64;

  auto stage = [&](int buf, int ktE) {
    int idx = t, row = idx >> 2, ch = idx & 3;
    gl_lds16(A + (size_t)(bm + row) * Kd + ktE + ch * 8, &As[buf][idx * 8]);
    gl_lds16(B + (size_t)(bn + row) * Kd + ktE + ch * 8, &Bs[buf][idx * 8]);
    idx = t + 256; row = idx >> 2; ch = idx & 3;
    gl_lds16(A + (size_t)(bm + row) * Kd + ktE + ch * 8, &As[buf][idx * 8]);
    gl_lds16(B + (size_t)(bn + row) * Kd + ktE + ch * 8, &Bs[buf][idx * 8]);
  };

  f32x4 acc[4][4] = {};
  const int nK = Kd >> 5;

  stage(0, 0);
  for (int k5 = 0; k5 < nK; ++k5) {
    const int cur = k5 & 1;
    if (k5 + 1 < nK) {
      stage(cur ^ 1, (k5 + 1) << 5);
      asm volatile("s_waitcnt vmcnt(4)" ::: "memory");
    } else {
      asm volatile("s_waitcnt vmcnt(0)" ::: "memory");
    }
    __builtin_amdgcn_s_barrier();

    bf16x8 af[4], bfr[4];
#pragma unroll
    for (int m = 0; m < 4; ++m)
      af[m] = *(const bf16x8*)&As[cur][(wr + m * 16 + lr) * 32 + lg * 8];
#pragma unroll
    for (int n = 0; n < 4; ++n)
      bfr[n] = *(const bf16x8*)&Bs[cur][(wc + n * 16 + lr) * 32 + lg * 8];
#pragma unroll
    for (int m = 0; m < 4; ++m)
#pragma unroll
      for (int n = 0; n < 4; ++n)
        acc[m][n] = __builtin_amdgcn_mfma_f32_16x16x32_bf16(af[m], bfr[n], acc[m][n], 0, 0, 0);

    __builtin_amdgcn_s_barrier();
  }

#pragma unroll
  for (int m = 0; m < 4; ++m)
#pragma unroll
    for (int n = 0; n < 4; ++n)
#pragma unroll
      for (int j = 0; j < 4; ++j) {
        int row = bm + wr + m * 16 + lg * 4 + j;
        int col = bn + wc + n * 16 + lr;
        float v = acc[m][n][j] * scale;
        if (OUT_BF16) {
          ((ushort*)C)[(size_t)row * N + col] = f2bu(v);
        } else {
          ((float*)C)[(size_t)row * N + col] = v;
        }
      }
}

__global__ __launch_bounds__(256)
void gemm_bt_f32(const ushort* __restrict__ A, const ushort* __restrict__ B, float* __restrict__ C,
                 int M, int N, int Kd, float scale) {
  __shared__ __attribute__((aligned(16))) ushort As[2][4096];
  __shared__ __attribute__((aligned(16))) ushort Bs[2][4096];
  gemm_body<0>(A, B, C, M, N, Kd, scale, blockIdx.x * 128, blockIdx.y * 128, As, Bs);
}

// fused QKV projection: grid.y in [0,24): y>>3 selects {Q,K,V}
__global__ __launch_bounds__(256)
void gemm_qkv(const ushort* __restrict__ A, const ushort* __restrict__ Wq, const ushort* __restrict__ Wk,
              const ushort* __restrict__ Wv, ushort* __restrict__ Qo, ushort* __restrict__ Ko,
              ushort* __restrict__ Vo, int M, int Kd) {
  __shared__ __attribute__((aligned(16))) ushort As[2][4096];
  __shared__ __attribute__((aligned(16))) ushort Bs[2][4096];
  int by = blockIdx.y;
  int which = by >> 3;
  const ushort* B = which == 0 ? Wq : which == 1 ? Wk : Wv;
  ushort* C       = which == 0 ? Qo : which == 1 ? Ko : Vo;
  float scale = which == 0 ? 0.125f : 1.0f;  // fold 1/sqrt(64) into Q
  gemm_body<1>(A, B, C, M, 1024, Kd, scale, blockIdx.x * 128, (by & 7) * 128, As, Bs);
}

// online softmax over one 64-wide score tile s4[c][j] (k = c*16+lg*4+j, q = 16 lanes of lr).
__device__ __forceinline__ void online_sm(f32x4 s4[4], float& m_, float& l_, f32x4 o[4],
                                          int lg, bf16x8& pa0_out, bf16x8& pa1_out) {
  float tm = NEGF;
#pragma unroll
  for (int c = 0; c < 4; ++c)
#pragma unroll
    for (int j = 0; j < 4; ++j) tm = fmaxf(tm, s4[c][j]);
  tm = fmaxf(tm, __shfl_xor(tm, 16));
  tm = fmaxf(tm, __shfl_xor(tm, 32));

  bool need = !__all(tm - m_ <= 8.0f);  // defer-max (T13)
  float mn = need ? fmaxf(m_, tm) : m_;
  float scl = mn * LOG2E;
  if (need) {
    float alpha = exp2f(m_ * LOG2E - scl);
    m_ = mn;
    l_ *= alpha;
    float a0 = __shfl(alpha, lg * 4 + 0, 16);
    float a1 = __shfl(alpha, lg * 4 + 1, 16);
    float a2 = __shfl(alpha, lg * 4 + 2, 16);
    float a3 = __shfl(alpha, lg * 4 + 3, 16);
#pragma unroll
    for (int dt = 0; dt < 4; ++dt) {
      o[dt][0] *= a0; o[dt][1] *= a1; o[dt][2] *= a2; o[dt][3] *= a3;
    }
  }

  float rs = 0.f;
#pragma unroll
  for (int c = 0; c < 4; ++c)
#pragma unroll
    for (int j = 0; j < 4; ++j) {
      float p = exp2f(s4[c][j] * LOG2E - scl);
      rs += p;
      s4[c][j] = p;
    }
  rs += __shfl_xor(rs, 16);
  rs += __shfl_xor(rs, 32);
  l_ += rs;

  union { bf16x8 v; ushort u[8]; } pa0, pa1;
#pragma unroll
  for (int j = 0; j < 4; ++j) {
    pa0.u[j]     = f2bu(s4[0][j]);
    pa0.u[4 + j] = f2bu(s4[1][j]);
    pa1.u[j]     = f2bu(s4[2][j]);
    pa1.u[4 + j] = f2bu(s4[3][j]);
  }
  pa0_out = pa0.v;
  pa1_out = pa1.v;
}

// ---- flash attention: 8 waves, tile-per-wave-group, double-buffered K/V, counted vmcnt ----
// grid: 512 blocks = 16 pairs x 32 (b,h). waves 0-3 -> q-tile A=p, waves 4-7 -> B=31-p.
__global__ __launch_bounds__(512, 4)
void attn_k(const ushort* __restrict__ Q, const ushort* __restrict__ K,
            const ushort* __restrict__ V, const int* __restrict__ mask,
            ushort* __restrict__ O) {
  const int S = 2048, D = 1024;
  __shared__ __attribute__((aligned(16))) ushort Ks[2][4096];  // 16B-chunk XOR-swizzled rows
  __shared__ __attribute__((aligned(16))) ushort Vs[2][4096];  // subtiled [d>>4][k>>2][k&3][d&15]
  __shared__ unsigned long long Msb[32];

  const int t = threadIdx.x;
  const int l = t & 63, w = t >> 6;        // w in 0..7
  const int wi = w & 3;                    // sub-wave row group within the tile
  const int wg = w >> 2;                   // 0 = tile A, 1 = tile B
  const int lr = l & 15, lg = l >> 4;

  // decode; co-resident blocks (f, f+256) get complementary p -> per-CU total = 49 iters
  int f = blockIdx.x;
  int pp = (f >> 3) & 15;
  int p  = ((f >> 8) & 1) ? 15 - pp : pp;
  int bh = (f & 7) | ((f >> 7) << 3);
  int h = bh & 15, b = bh >> 4;
  const int qA = p, qB = 31 - p;
  const int nt = qB + 1;
  const int qt = wg ? qB : qA;             // this wave's q-tile
  const size_t bS = (size_t)b * S;

  const ushort* qptr = Q + (bS + qt * 64 + wi * 16 + lr) * D + h * 64;
  bf16x8 qf0 = *(const bf16x8*)(qptr + lg * 8);
  bf16x8 qf1 = *(const bf16x8*)(qptr + 32 + lg * 8);

  const ushort* Kbh = K + bS * D + h * 64;
  const ushort* Vbh = V + bS * D + h * 64;
  const int* mbase = mask + bS;

  // precompute per-k-tile key-pad ballots (keeps loop VMEM = staging only)
  for (int kk = w; kk < nt; kk += 8) {
    unsigned long long mb = __ballot(mbase[kk * 64 + l] != 0);
    if (l == 0) Msb[kk] = mb;
  }
  __builtin_amdgcn_sched_barrier(0);  // keep mask loads out of the staged-vmcnt window

  float m_ = -INFINITY, l_ = 0.f;
  f32x4 o[4] = {};

  // stage(buf, kt): 2 global_load_lds per thread (1 K chunk + 1 V chunk), 512 threads
  auto stage = [&](int buf, int kt) {
    { int idx = t; int row = idx >> 3, ch = idx & 7;
      gl_lds16(Kbh + (size_t)(kt * 64 + row) * D + ((ch ^ (row & 7)) * 8), &Ks[buf][idx * 8]); }
    { int idx = t; int dg = idx >> 7, kq = (idx >> 3) & 15, jj = (idx >> 1) & 3, hf = idx & 1;
      gl_lds16(Vbh + (size_t)(kt * 64 + kq * 4 + jj) * D + dg * 16 + hf * 8, &Vs[buf][idx * 8]); }
  };

  stage(0, 0);

  for (int kt = 0; kt < nt; ++kt) {
    const int cur = kt & 1;
    if (kt + 1 < nt) {
      stage(cur ^ 1, kt + 1);
      asm volatile("s_waitcnt vmcnt(2) lgkmcnt(0)" ::: "memory");
    } else {
      asm volatile("s_waitcnt vmcnt(0) lgkmcnt(0)" ::: "memory");
    }
    __builtin_amdgcn_s_barrier();   // cur buffer fully staged (each wave waited its own loads)

    if (kt <= qt) {                 // wave-uniform activity test
      unsigned long long mb = Msb[kt];
      const bool diag = (kt == qt);
      const int cmax = diag ? wi : 3;

      // swapped QK^T: s4[c][j] = S[q = wi*16+lr][k = c*16 + lg*4 + j]
      f32x4 s4[4];
      __builtin_amdgcn_s_setprio(1);
#pragma unroll
      for (int c = 0; c < 4; ++c) {
        if (c <= cmax) {
          int row = c * 16 + lr;
          bf16x8 kf0 = *(const bf16x8*)&Ks[cur][row * 64 + ((lg ^ (row & 7)) << 3)];
          bf16x8 kf1 = *(const bf16x8*)&Ks[cur][row * 64 + (((4 + lg) ^ (row & 7)) << 3)];
          f32x4 sc = {0.f, 0.f, 0.f, 0.f};
          sc = __builtin_amdgcn_mfma_f32_16x16x32_bf16(kf0, qf0, sc, 0, 0, 0);
          sc = __builtin_amdgcn_mfma_f32_16x16x32_bf16(kf1, qf1, sc, 0, 0, 0);
          if (diag && c == cmax) {
            int qg = wi * 16 + lr, kb = c * 16 + lg * 4;
#pragma unroll
            for (int j = 0; j < 4; ++j)
              if (kb + j > qg) sc[j] = NEGF;
          }
          s4[c] = sc;
        } else {
          s4[c] = (f32x4){NEGF, NEGF, NEGF, NEGF};
        }
      }
      __builtin_amdgcn_s_setprio(0);

      // key-pad mask (skipped when all ones)
      if (~mb != 0ull) {
#pragma unroll
        for (int c = 0; c < 4; ++c)
#pragma unroll
          for (int j = 0; j < 4; ++j)
            if (!((mb >> (c * 16 + lg * 4 + j)) & 1)) s4[c][j] = NEGF;
      }

      bf16x8 pa0, pa1;
      online_sm(s4, m_, l_, o, lg, pa0, pa1);

      // PV: tr-read V fragments, MFMA into o
      __builtin_amdgcn_s_setprio(1);
#pragma unroll
      for (int dt = 0; dt < 4; ++dt) {
        const __attribute__((address_space(3))) ushort* vp =
            (const __attribute__((address_space(3))) ushort*)&Vs[cur][0] + dt * 1024 + lg * 64 + lr * 4;
        bf16x4 h0, h1, h2, h3;
        asm volatile(
            "ds_read_b64_tr_b16 %0, %4\n\t"
            "ds_read_b64_tr_b16 %1, %4 offset:512\n\t"
            "ds_read_b64_tr_b16 %2, %4 offset:1024\n\t"
            "ds_read_b64_tr_b16 %3, %4 offset:1536\n\t"
            "s_waitcnt lgkmcnt(0)"
            : "=&v"(h0), "=&v"(h1), "=&v"(h2), "=&v"(h3)
            : "v"(vp));
        bf16x8 vb0 = __builtin_shufflevector(h0, h1, 0, 1, 2, 3, 4, 5, 6, 7);
        bf16x8 vb1 = __builtin_shufflevector(h2, h3, 0, 1, 2, 3, 4, 5, 6, 7);
        o[dt] = __builtin_amdgcn_mfma_f32_16x16x32_bf16(pa0, vb0, o[dt], 0, 0, 0);
        o[dt] = __builtin_amdgcn_mfma_f32_16x16x32_bf16(pa1, vb1, o[dt], 0, 0, 0);
      }
      __builtin_amdgcn_s_setprio(0);
    }

    __builtin_amdgcn_s_barrier();   // all reads of cur done before next iter overwrites it
  }

  // epilogue: normalize and write this wave's 16 rows
  float inv = 1.0f / l_;
  float v0 = __shfl(inv, lg * 4 + 0, 16);
  float v1 = __shfl(inv, lg * 4 + 1, 16);
  float v2 = __shfl(inv, lg * 4 + 2, 16);
  float v3 = __shfl(inv, lg * 4 + 3, 16);
#pragma unroll
  for (int dt = 0; dt < 4; ++dt) {
    size_t col = (size_t)h * 64 + dt * 16 + lr;
    size_t r0 = bS + qt * 64 + wi * 16 + lg * 4;
    O[(r0 + 0) * D + col] = f2bu(o[dt][0] * v0);
    O[(r0 + 1) * D + col] = f2bu(o[dt][1] * v1);
    O[(r0 + 2) * D + col] = f2bu(o[dt][2] * v2);
    O[(r0 + 3) * D + col] = f2bu(o[dt][3] * v3);
  }
}

extern "C" void kernel_launch(void* const* d_in, const int* in_sizes, int n_in,
                              void* d_out, int out_size, void* d_ws, size_t ws_size,
                              hipStream_t stream) {
  const float* x    = (const float*)d_in[0];
  const int*   mask = (const int*)d_in[1];
  const float* Wq   = (const float*)d_in[2];
  const float* Wk   = (const float*)d_in[3];
  const float* Wv   = (const float*)d_in[4];
  const float* Wo   = (const float*)d_in[5];
  float* out = (float*)d_out;

  const int B = 2, S = 2048, D = 1024;
  const int M = B * S;

  // 48 MB peak (proven footprint)
  char* ws = (char*)d_ws;
  ushort* xb  = (ushort*)(ws);                  // 8 MB
  ushort* wqb = (ushort*)(ws + (8ull  << 20));  // 2 MB
  ushort* wkb = (ushort*)(ws + (10ull << 20));
  ushort* wvb = (ushort*)(ws + (12ull << 20));
  ushort* wob = (ushort*)(ws + (14ull << 20));
  ushort* Qb  = (ushort*)(ws + (16ull << 20));  // 8 MB
  ushort* Kb  = (ushort*)(ws + (24ull << 20));
  ushort* Vb  = (ushort*)(ws + (32ull << 20));
  ushort* AO  = (ushort*)(ws + (40ull << 20));

  int nx4 = M * D / 4;  // 1048576
  cast_bf16_k<<<(nx4 + 255) / 256, 256, 0, stream>>>(x, xb, nx4);
  cast_w4_k<<<4096, 256, 0, stream>>>(Wq, Wk, Wv, Wo, wqb, wkb, wvb, wob);

  dim3 gq(M / 128, 24);
  gemm_qkv<<<gq, 256, 0, stream>>>(xb, wqb, wkb, wvb, Qb, Kb, Vb, M, D);

  attn_k<<<512, 512, 0, stream>>>(Qb, Kb, Vb, mask, AO);

  dim3 gp(M / 128, D / 128);
  gemm_bt_f32<<<gp, 256, 0, stream>>>(AO, wob, out, M, D, D, 1.0f);
}

// Round 7
// 122.950 us; speedup vs baseline: 2.2779x; 1.0351x over previous
//
#include <hip/hip_runtime.h>
#include <hip/hip_bf16.h>

typedef __attribute__((ext_vector_type(8))) short bf16x8;
typedef __attribute__((ext_vector_type(4))) short bf16x4;
typedef __attribute__((ext_vector_type(4))) float f32x4;

#define LOG2E 1.4426950408889634f
#define NEGF  -3.0e38f

__device__ __forceinline__ void gl_lds16(const void* g, void* l) {
  __builtin_amdgcn_global_load_lds((const __attribute__((address_space(1))) void*)g,
                                   (__attribute__((address_space(3))) void*)l, 16, 0, 0);
}

__device__ __forceinline__ ushort f2bu(float x) {
  __hip_bfloat16 h = __float2bfloat16(x);
  return *(ushort*)&h;
}

// ---- f32 -> bf16 cast for x ----
__global__ __launch_bounds__(256) void cast_bf16_k(const float* __restrict__ in,
                                                   ushort* __restrict__ out, int n4) {
  int i = blockIdx.x * 256 + threadIdx.x;
  if (i >= n4) return;
  float4 f = ((const float4*)in)[i];
  ushort4 u;
  u.x = f2bu(f.x); u.y = f2bu(f.y); u.z = f2bu(f.z); u.w = f2bu(f.w);
  ((ushort4*)out)[i] = u;
}

// ---- fused cast of the 4 weight matrices (each 1024x1024 = 2^18 float4) ----
__global__ __launch_bounds__(256) void cast_w4_k(const float* __restrict__ a, const float* __restrict__ b,
                                                 const float* __restrict__ c, const float* __restrict__ d,
                                                 ushort* __restrict__ oa, ushort* __restrict__ ob,
                                                 ushort* __restrict__ oc, ushort* __restrict__ od) {
  int i = blockIdx.x * 256 + threadIdx.x;
  int wsel = i >> 18, j = i & 262143;
  const float* src = wsel == 0 ? a : wsel == 1 ? b : wsel == 2 ? c : d;
  ushort* dst      = wsel == 0 ? oa : wsel == 1 ? ob : wsel == 2 ? oc : od;
  float4 f = ((const float4*)src)[j];
  ushort4 u;
  u.x = f2bu(f.x); u.y = f2bu(f.y); u.z = f2bu(f.z); u.w = f2bu(f.w);
  ((ushort4*)dst)[j] = u;
}

// ---- GEMM tile body: ring-3 LDS, depth-2 prefetch, counted vmcnt ----
template<int OUT_BF16>
__device__ __forceinline__ void gemm_body(const ushort* __restrict__ A, const ushort* __restrict__ B,
                                          void* __restrict__ C, int M, int N, int Kd, float scale,
                                          int bm, int bn, ushort (*As)[4096], ushort (*Bs)[4096]) {
  const int t  = threadIdx.x;
  const int l  = t & 63;
  const int w  = t >> 6;
  const int lr = l & 15, lg = l >> 4;
  const int wr = (w >> 1) * 64, wc = (w & 1) * 64;

  auto stage = [&](int buf, int ktE) {
    int idx = t, row = idx >> 2, ch = idx & 3;
    gl_lds16(A + (size_t)(bm + row) * Kd + ktE + ch * 8, &As[buf][idx * 8]);
    gl_lds16(B + (size_t)(bn + row) * Kd + ktE + ch * 8, &Bs[buf][idx * 8]);
    idx = t + 256; row = idx >> 2; ch = idx & 3;
    gl_lds16(A + (size_t)(bm + row) * Kd + ktE + ch * 8, &As[buf][idx * 8]);
    gl_lds16(B + (size_t)(bn + row) * Kd + ktE + ch * 8, &Bs[buf][idx * 8]);
  };

  f32x4 acc[4][4] = {};
  const int nK = Kd >> 5;   // 32-wide K-steps

  stage(0, 0);
  stage(1, 32);
  int cur = 0;
  for (int k5 = 0; k5 < nK; ++k5) {
    if (k5 + 2 < nK) {
      int nb = cur + 2; if (nb >= 3) nb -= 3;
      stage(nb, (k5 + 2) << 5);
      asm volatile("s_waitcnt vmcnt(8)" ::: "memory");   // k5's 4 loads done; 8 in flight
    } else if (k5 + 1 < nK) {
      asm volatile("s_waitcnt vmcnt(4)" ::: "memory");
    } else {
      asm volatile("s_waitcnt vmcnt(0)" ::: "memory");
    }
    __builtin_amdgcn_s_barrier();

    bf16x8 af[4], bfr[4];
#pragma unroll
    for (int m = 0; m < 4; ++m)
      af[m] = *(const bf16x8*)&As[cur][(wr + m * 16 + lr) * 32 + lg * 8];
#pragma unroll
    for (int n = 0; n < 4; ++n)
      bfr[n] = *(const bf16x8*)&Bs[cur][(wc + n * 16 + lr) * 32 + lg * 8];
#pragma unroll
    for (int m = 0; m < 4; ++m)
#pragma unroll
      for (int n = 0; n < 4; ++n)
        acc[m][n] = __builtin_amdgcn_mfma_f32_16x16x32_bf16(af[m], bfr[n], acc[m][n], 0, 0, 0);

    __builtin_amdgcn_s_barrier();  // WAR: buf cur gets overwritten at iter k5+3 (ring-3)
    ++cur; if (cur >= 3) cur -= 3;
  }

#pragma unroll
  for (int m = 0; m < 4; ++m)
#pragma unroll
    for (int n = 0; n < 4; ++n)
#pragma unroll
      for (int j = 0; j < 4; ++j) {
        int row = bm + wr + m * 16 + lg * 4 + j;
        int col = bn + wc + n * 16 + lr;
        float v = acc[m][n][j] * scale;
        if (OUT_BF16) {
          ((ushort*)C)[(size_t)row * N + col] = f2bu(v);
        } else {
          ((float*)C)[(size_t)row * N + col] = v;
        }
      }
}

__global__ __launch_bounds__(256)
void gemm_bt_f32(const ushort* __restrict__ A, const ushort* __restrict__ B, float* __restrict__ C,
                 int M, int N, int Kd, float scale) {
  __shared__ __attribute__((aligned(16))) ushort As[3][4096];
  __shared__ __attribute__((aligned(16))) ushort Bs[3][4096];
  gemm_body<0>(A, B, C, M, N, Kd, scale, blockIdx.x * 128, blockIdx.y * 128, As, Bs);
}

// fused QKV projection: grid.y in [0,24): y>>3 selects {Q,K,V}
__global__ __launch_bounds__(256)
void gemm_qkv(const ushort* __restrict__ A, const ushort* __restrict__ Wq, const ushort* __restrict__ Wk,
              const ushort* __restrict__ Wv, ushort* __restrict__ Qo, ushort* __restrict__ Ko,
              ushort* __restrict__ Vo, int M, int Kd) {
  __shared__ __attribute__((aligned(16))) ushort As[3][4096];
  __shared__ __attribute__((aligned(16))) ushort Bs[3][4096];
  int by = blockIdx.y;
  int which = by >> 3;
  const ushort* B = which == 0 ? Wq : which == 1 ? Wk : Wv;
  ushort* C       = which == 0 ? Qo : which == 1 ? Ko : Vo;
  float scale = which == 0 ? 0.125f : 1.0f;  // fold 1/sqrt(64) into Q
  gemm_body<1>(A, B, C, M, 1024, Kd, scale, blockIdx.x * 128, (by & 7) * 128, As, Bs);
}

// online softmax over one 64-wide score tile s4[c][j] (k = c*16+lg*4+j, q = 16 lanes of lr).
__device__ __forceinline__ void online_sm(f32x4 s4[4], float& m_, float& l_, f32x4 o[4],
                                          int lg, bf16x8& pa0_out, bf16x8& pa1_out) {
  float tm = NEGF;
#pragma unroll
  for (int c = 0; c < 4; ++c)
#pragma unroll
    for (int j = 0; j < 4; ++j) tm = fmaxf(tm, s4[c][j]);
  tm = fmaxf(tm, __shfl_xor(tm, 16));
  tm = fmaxf(tm, __shfl_xor(tm, 32));

  bool need = !__all(tm - m_ <= 8.0f);  // defer-max (T13)
  float mn = need ? fmaxf(m_, tm) : m_;
  float scl = mn * LOG2E;
  if (need) {
    float alpha = exp2f(m_ * LOG2E - scl);
    m_ = mn;
    l_ *= alpha;
    float a0 = __shfl(alpha, lg * 4 + 0, 16);
    float a1 = __shfl(alpha, lg * 4 + 1, 16);
    float a2 = __shfl(alpha, lg * 4 + 2, 16);
    float a3 = __shfl(alpha, lg * 4 + 3, 16);
#pragma unroll
    for (int dt = 0; dt < 4; ++dt) {
      o[dt][0] *= a0; o[dt][1] *= a1; o[dt][2] *= a2; o[dt][3] *= a3;
    }
  }

  float rs = 0.f;
#pragma unroll
  for (int c = 0; c < 4; ++c)
#pragma unroll
    for (int j = 0; j < 4; ++j) {
      float p = exp2f(s4[c][j] * LOG2E - scl);
      rs += p;
      s4[c][j] = p;
    }
  rs += __shfl_xor(rs, 16);
  rs += __shfl_xor(rs, 32);
  l_ += rs;

  union { bf16x8 v; ushort u[8]; } pa0, pa1;
#pragma unroll
  for (int j = 0; j < 4; ++j) {
    pa0.u[j]     = f2bu(s4[0][j]);
    pa0.u[4 + j] = f2bu(s4[1][j]);
    pa1.u[j]     = f2bu(s4[2][j]);
    pa1.u[4 + j] = f2bu(s4[3][j]);
  }
  pa0_out = pa0.v;
  pa1_out = pa1.v;
}

// ---- flash attention: 8 waves, tile-per-wave-group, ring-4 K/V, depth-2 prefetch ----
// grid: 512 blocks = 16 pairs x 32 (b,h). waves 0-3 -> q-tile A=p, waves 4-7 -> B=31-p.
__global__ __launch_bounds__(512, 4)
void attn_k(const ushort* __restrict__ Q, const ushort* __restrict__ K,
            const ushort* __restrict__ V, const int* __restrict__ mask,
            ushort* __restrict__ O) {
  const int S = 2048, D = 1024;
  __shared__ __attribute__((aligned(16))) ushort Ks[4][4096];  // 16B-chunk XOR-swizzled rows
  __shared__ __attribute__((aligned(16))) ushort Vs[4][4096];  // subtiled [d>>4][k>>2][k&3][d&15]
  __shared__ unsigned long long Msb[32];

  const int t = threadIdx.x;
  const int l = t & 63, w = t >> 6;        // w in 0..7
  const int wi = w & 3;                    // sub-wave row group within the tile
  const int wg = w >> 2;                   // 0 = tile A, 1 = tile B
  const int lr = l & 15, lg = l >> 4;

  // decode; co-resident blocks (f, f+256) get complementary p -> per-CU total = 49 iters
  int f = blockIdx.x;
  int pp = (f >> 3) & 15;
  int p  = ((f >> 8) & 1) ? 15 - pp : pp;
  int bh = (f & 7) | ((f >> 7) << 3);
  int h = bh & 15, b = bh >> 4;
  const int qA = p, qB = 31 - p;
  const int nt = qB + 1;                   // nt >= 17 always
  const int qt = wg ? qB : qA;             // this wave's q-tile
  const size_t bS = (size_t)b * S;

  const ushort* qptr = Q + (bS + qt * 64 + wi * 16 + lr) * D + h * 64;
  bf16x8 qf0 = *(const bf16x8*)(qptr + lg * 8);
  bf16x8 qf1 = *(const bf16x8*)(qptr + 32 + lg * 8);

  const ushort* Kbh = K + bS * D + h * 64;
  const ushort* Vbh = V + bS * D + h * 64;
  const int* mbase = mask + bS;

  // precompute per-k-tile key-pad ballots (keeps loop VMEM = staging only)
  for (int kk = w; kk < nt; kk += 8) {
    unsigned long long mb = __ballot(mbase[kk * 64 + l] != 0);
    if (l == 0) Msb[kk] = mb;
  }
  asm volatile("s_waitcnt lgkmcnt(0)" ::: "memory");  // Msb writes in LDS before first barrier
  __builtin_amdgcn_sched_barrier(0);

  float m_ = -INFINITY, l_ = 0.f;
  f32x4 o[4] = {};

  // stage(buf, kt): 2 global_load_lds per thread (1 K chunk + 1 V chunk), 512 threads
  auto stage = [&](int buf, int kt) {
    { int idx = t; int row = idx >> 3, ch = idx & 7;
      gl_lds16(Kbh + (size_t)(kt * 64 + row) * D + ((ch ^ (row & 7)) * 8), &Ks[buf][idx * 8]); }
    { int idx = t; int dg = idx >> 7, kq = (idx >> 3) & 15, jj = (idx >> 1) & 3, hf = idx & 1;
      gl_lds16(Vbh + (size_t)(kt * 64 + kq * 4 + jj) * D + dg * 16 + hf * 8, &Vs[buf][idx * 8]); }
  };

  stage(0, 0);
  stage(1, 1);

  for (int kt = 0; kt < nt; ++kt) {
    const int cur = kt & 3;
    // depth-2 pipeline: kt's loads were issued 2 iterations ago (~2x iter-time lead).
    // Ring-4 => stage(kt+2) overwrites the buffer read at iter kt-2, whose reads finished
    // before barrier_{kt-1}, which all waves passed before reaching this stage. One barrier.
    if (kt + 2 < nt) {
      stage((kt + 2) & 3, kt + 2);
      asm volatile("s_waitcnt vmcnt(4)" ::: "memory");
    } else if (kt + 1 < nt) {
      asm volatile("s_waitcnt vmcnt(2)" ::: "memory");
    } else {
      asm volatile("s_waitcnt vmcnt(0)" ::: "memory");
    }
    __builtin_amdgcn_s_barrier();   // cur buffer fully staged for all waves

    if (kt <= qt) {                 // wave-uniform activity test
      unsigned long long mb = Msb[kt];
      const bool diag = (kt == qt);
      const int cmax = diag ? wi : 3;

      // swapped QK^T: s4[c][j] = S[q = wi*16+lr][k = c*16 + lg*4 + j]
      f32x4 s4[4];
      __builtin_amdgcn_s_setprio(1);
#pragma unroll
      for (int c = 0; c < 4; ++c) {
        if (c <= cmax) {
          int row = c * 16 + lr;
          bf16x8 kf0 = *(const bf16x8*)&Ks[cur][row * 64 + ((lg ^ (row & 7)) << 3)];
          bf16x8 kf1 = *(const bf16x8*)&Ks[cur][row * 64 + (((4 + lg) ^ (row & 7)) << 3)];
          f32x4 sc = {0.f, 0.f, 0.f, 0.f};
          sc = __builtin_amdgcn_mfma_f32_16x16x32_bf16(kf0, qf0, sc, 0, 0, 0);
          sc = __builtin_amdgcn_mfma_f32_16x16x32_bf16(kf1, qf1, sc, 0, 0, 0);
          if (diag && c == cmax) {
            int qg = wi * 16 + lr, kb = c * 16 + lg * 4;
#pragma unroll
            for (int j = 0; j < 4; ++j)
              if (kb + j > qg) sc[j] = NEGF;
          }
          s4[c] = sc;
        } else {
          s4[c] = (f32x4){NEGF, NEGF, NEGF, NEGF};
        }
      }
      __builtin_amdgcn_s_setprio(0);

      // key-pad mask (skipped when all ones)
      if (~mb != 0ull) {
#pragma unroll
        for (int c = 0; c < 4; ++c)
#pragma unroll
          for (int j = 0; j < 4; ++j)
            if (!((mb >> (c * 16 + lg * 4 + j)) & 1)) s4[c][j] = NEGF;
      }

      bf16x8 pa0, pa1;
      online_sm(s4, m_, l_, o, lg, pa0, pa1);

      // PV: tr-read V fragments, MFMA into o
      __builtin_amdgcn_s_setprio(1);
#pragma unroll
      for (int dt = 0; dt < 4; ++dt) {
        const __attribute__((address_space(3))) ushort* vp =
            (const __attribute__((address_space(3))) ushort*)&Vs[cur][0] + dt * 1024 + lg * 64 + lr * 4;
        bf16x4 h0, h1, h2, h3;
        asm volatile(
            "ds_read_b64_tr_b16 %0, %4\n\t"
            "ds_read_b64_tr_b16 %1, %4 offset:512\n\t"
            "ds_read_b64_tr_b16 %2, %4 offset:1024\n\t"
            "ds_read_b64_tr_b16 %3, %4 offset:1536\n\t"
            "s_waitcnt lgkmcnt(0)"
            : "=&v"(h0), "=&v"(h1), "=&v"(h2), "=&v"(h3)
            : "v"(vp));
        bf16x8 vb0 = __builtin_shufflevector(h0, h1, 0, 1, 2, 3, 4, 5, 6, 7);
        bf16x8 vb1 = __builtin_shufflevector(h2, h3, 0, 1, 2, 3, 4, 5, 6, 7);
        o[dt] = __builtin_amdgcn_mfma_f32_16x16x32_bf16(pa0, vb0, o[dt], 0, 0, 0);
        o[dt] = __builtin_amdgcn_mfma_f32_16x16x32_bf16(pa1, vb1, o[dt], 0, 0, 0);
      }
      __builtin_amdgcn_s_setprio(0);
    }
  }

  // epilogue: normalize and write this wave's 16 rows
  float inv = 1.0f / l_;
  float v0 = __shfl(inv, lg * 4 + 0, 16);
  float v1 = __shfl(inv, lg * 4 + 1, 16);
  float v2 = __shfl(inv, lg * 4 + 2, 16);
  float v3 = __shfl(inv, lg * 4 + 3, 16);
#pragma unroll
  for (int dt = 0; dt < 4; ++dt) {
    size_t col = (size_t)h * 64 + dt * 16 + lr;
    size_t r0 = bS + qt * 64 + wi * 16 + lg * 4;
    O[(r0 + 0) * D + col] = f2bu(o[dt][0] * v0);
    O[(r0 + 1) * D + col] = f2bu(o[dt][1] * v1);
    O[(r0 + 2) * D + col] = f2bu(o[dt][2] * v2);
    O[(r0 + 3) * D + col] = f2bu(o[dt][3] * v3);
  }
}

extern "C" void kernel_launch(void* const* d_in, const int* in_sizes, int n_in,
                              void* d_out, int out_size, void* d_ws, size_t ws_size,
                              hipStream_t stream) {
  const float* x    = (const float*)d_in[0];
  const int*   mask = (const int*)d_in[1];
  const float* Wq   = (const float*)d_in[2];
  const float* Wk   = (const float*)d_in[3];
  const float* Wv   = (const float*)d_in[4];
  const float* Wo   = (const float*)d_in[5];
  float* out = (float*)d_out;

  const int B = 2, S = 2048, D = 1024;
  const int M = B * S;

  // 48 MB peak (proven footprint)
  char* ws = (char*)d_ws;
  ushort* xb  = (ushort*)(ws);                  // 8 MB
  ushort* wqb = (ushort*)(ws + (8ull  << 20));  // 2 MB
  ushort* wkb = (ushort*)(ws + (10ull << 20));
  ushort* wvb = (ushort*)(ws + (12ull << 20));
  ushort* wob = (ushort*)(ws + (14ull << 20));
  ushort* Qb  = (ushort*)(ws + (16ull << 20));  // 8 MB
  ushort* Kb  = (ushort*)(ws + (24ull << 20));
  ushort* Vb  = (ushort*)(ws + (32ull << 20));
  ushort* AO  = (ushort*)(ws + (40ull << 20));

  int nx4 = M * D / 4;  // 1048576
  cast_bf16_k<<<(nx4 + 255) / 256, 256, 0, stream>>>(x, xb, nx4);
  cast_w4_k<<<4096, 256, 0, stream>>>(Wq, Wk, Wv, Wo, wqb, wkb, wvb, wob);

  dim3 gq(M / 128, 24);
  gemm_qkv<<<gq, 256, 0, stream>>>(xb, wqb, wkb, wvb, Qb, Kb, Vb, M, D);

  attn_k<<<512, 512, 0, stream>>>(Qb, Kb, Vb, mask, AO);

  dim3 gp(M / 128, D / 128);
  gemm_bt_f32<<<gp, 256, 0, stream>>>(AO, wob, out, M, D, D, 1.0f);
}